// Round 1
// baseline (43.393 us; speedup 1.0000x reference)
//
#include <hip/hip_runtime.h>

// Satellite-specific per-image affine: out = valid(sid) ? x*w[sid]+b[sid] : x
// x: (8,16,1,512,512) fp32 -> 33,554,432 elems = 8,388,608 float4
// Each image is 512*512/4 = 65536 = 2^16 float4 -> image index = i >> 16.
// Memory-bound: 268 MB total traffic, roofline ~43 us @ 6.3 TB/s.

#define IMG_SHIFT 16  // log2(512*512/4)
#define NUM_SAT 8

__global__ __launch_bounds__(256) void sat_affine_kernel(
    const float4* __restrict__ x,
    const float*  __restrict__ weight,   // (8,1,1,1) flat
    const float*  __restrict__ bias,     // (8,1,1,1) flat
    const int*    __restrict__ ids,      // (8,16) flat = 128 entries
    float4*       __restrict__ out,
    int n4)
{
    const int stride = gridDim.x * blockDim.x;
    for (int i = blockIdx.x * blockDim.x + threadIdx.x; i < n4; i += stride) {
        const int img = i >> IMG_SHIFT;
        const int sid = ids[img];
        const bool valid = (sid >= 0) && (sid < NUM_SAT);
        const int sidc = valid ? sid : 0;
        // branchless: invalid ids -> identity affine (x*1+0 == x exactly in fp32)
        const float w = valid ? weight[sidc] : 1.0f;
        const float b = valid ? bias[sidc]   : 0.0f;

        const float4 v = x[i];
        float4 r;
        r.x = fmaf(v.x, w, b);
        r.y = fmaf(v.y, w, b);
        r.z = fmaf(v.z, w, b);
        r.w = fmaf(v.w, w, b);
        out[i] = r;
    }
}

extern "C" void kernel_launch(void* const* d_in, const int* in_sizes, int n_in,
                              void* d_out, int out_size, void* d_ws, size_t ws_size,
                              hipStream_t stream) {
    const float4* x      = (const float4*)d_in[0];
    const float*  weight = (const float*)d_in[1];
    const float*  bias   = (const float*)d_in[2];
    const int*    ids    = (const int*)d_in[3];
    float4* out = (float4*)d_out;

    const int n4 = out_size / 4;           // 8,388,608
    const int block = 256;
    int grid = (n4 + block - 1) / block;
    if (grid > 2048) grid = 2048;          // grid-stride the rest (Guideline 11)

    sat_affine_kernel<<<grid, block, 0, stream>>>(x, weight, bias, ids, out, n4);
}